// Round 8
// baseline (363.820 us; speedup 1.0000x reference)
//
#include <hip/hip_runtime.h>
#include <stdint.h>

#define M_DIM 8192
#define N_DIM 4096
#define K_DIM 4096

typedef float f32x4 __attribute__((ext_vector_type(4)));
typedef int   i32x4 __attribute__((ext_vector_type(4)));
typedef int   i32x8 __attribute__((ext_vector_type(8)));

// ---------------- fused amax (x and w) via uint-bits atomicMax ----------------
__global__ __launch_bounds__(256) void amax2_kernel(const float* __restrict__ x,
                                                    const float* __restrict__ wgt,
                                                    unsigned int* __restrict__ ws_u) {
    const int which = blockIdx.y;
    const float4* p = (const float4*)(which ? wgt : x);
    const int n4 = (which ? N_DIM : M_DIM) * (K_DIM / 4);
    int tid = blockIdx.x * blockDim.x + threadIdx.x;
    int stride = gridDim.x * blockDim.x;
    float m = 0.0f;
    for (int i = tid; i < n4; i += stride) {
        float4 v = p[i];
        m = fmaxf(m, fmaxf(fmaxf(fabsf(v.x), fabsf(v.y)),
                           fmaxf(fabsf(v.z), fabsf(v.w))));
    }
#pragma unroll
    for (int off = 32; off > 0; off >>= 1)
        m = fmaxf(m, __shfl_down(m, off, 64));
    __shared__ float sm[4];
    if ((threadIdx.x & 63) == 0) sm[threadIdx.x >> 6] = m;
    __syncthreads();
    if (threadIdx.x == 0) {
        m = fmaxf(fmaxf(sm[0], sm[1]), fmaxf(sm[2], sm[3]));
        atomicMax(ws_u + which, __float_as_uint(m));  // values >= 0: bit order == float order
    }
}

// ---------------- fused quantize f32 -> fp8 e4m3fn (packed 4/uint) -------------
__global__ __launch_bounds__(256) void quant2_kernel(const float* __restrict__ x,
                                                     const float* __restrict__ wgt,
                                                     unsigned int* __restrict__ xq,
                                                     unsigned int* __restrict__ wq,
                                                     const unsigned int* __restrict__ ws_u) {
    const int which = blockIdx.y;
    const float4* p = (const float4*)(which ? wgt : x);
    unsigned int* outp = which ? wq : xq;
    const int n4 = (which ? N_DIM : M_DIM) * (K_DIM / 4);
    float amax = fmaxf(__uint_as_float(ws_u[which]), 1e-12f);
    float scale = 448.0f / amax;
    int tid = blockIdx.x * blockDim.x + threadIdx.x;
    int stride = gridDim.x * blockDim.x;
    for (int i = tid; i < n4; i += stride) {
        float4 v = p[i];
        float a = fminf(fmaxf(v.x * scale, -448.0f), 448.0f);
        float b = fminf(fmaxf(v.y * scale, -448.0f), 448.0f);
        float c = fminf(fmaxf(v.z * scale, -448.0f), 448.0f);
        float d = fminf(fmaxf(v.w * scale, -448.0f), 448.0f);
        int w = __builtin_amdgcn_cvt_pk_fp8_f32(a, b, 0, false);
        w = __builtin_amdgcn_cvt_pk_fp8_f32(c, d, w, true);
        outp[i] = (unsigned int)w;
    }
}

// ---------------- MX-fp8 GEMM, 256x256, cluster-pipelined read||MFMA ----------
__device__ __forceinline__ void gld16(const void* g, void* l) {
    __builtin_amdgcn_global_load_lds(
        (const __attribute__((address_space(1))) void*)g,
        (__attribute__((address_space(3))) void*)l, 16, 0, 0);
}

#define MFMA_MX(a, b, c) __builtin_amdgcn_mfma_scale_f32_16x16x128_f8f6f4( \
    (a), (b), (c), 0, 0, 0, 0x7F7F7F7F, 0, 0x7F7F7F7F)
#define BAR()    __builtin_amdgcn_s_barrier()
#define VMCNT(n) asm volatile("s_waitcnt vmcnt(" #n ")" ::: "memory")
#define PRIO1()  __builtin_amdgcn_s_setprio(1)
#define PRIO0()  __builtin_amdgcn_s_setprio(0)

// LDS: A bufs [0,32K),[32K,64K); B bufs [64K,96K),[96K,128K).
// Tile [256 rows][128 B], 16B-chunk XOR swizzle (chunk ^= row&7); linear
// dest, pre-swizzled global source, XOR on read address (rule #21).
// Per tile: BOTH barriers adjacent at the top --
//   BAR#1 (all waves' reads of nbuf retired -- reads are fully consumed by
//   MFMAs via lgkmcnt before a wave can reach the barrier), then stage 8
//   units of t+1 into nbuf, VMCNT(8) (retires tile-t's 8 stages; issued a
//   full tile ago so ~zero stall), BAR#2 (tile t visible).
// Then an UNBROKEN read||MFMA stream in 8 clusters of 4 MFMAs with the
// next cluster's 2 ds-frag reads issued ahead -- compiler emits incremental
// lgkmcnt so the DS pipe streams under the matrix pipe (m196: fine
// interleave is the lever; no mid-tile barrier to lockstep the waves).
// Register plan = R4's proven flow: av[4] reused for rows+64.., <=8 frags live.
#define TILE_BODY(T, BUF)                                                      \
  {                                                                            \
    const uint8_t* lab = &lds[(BUF) * 32768];                                  \
    const uint8_t* lbb = &lds[65536 + (BUF) * 32768];                          \
    const int kn = ((T) + 1) * 128;                                            \
    BAR();                                                                     \
    stA((BUF) ^ 1, kn, 0);   stA((BUF) ^ 1, kn, 64);                           \
    stA((BUF) ^ 1, kn, 128); stA((BUF) ^ 1, kn, 192);                          \
    stB((BUF) ^ 1, kn, 0);   stB((BUF) ^ 1, kn, 64);                           \
    stB((BUF) ^ 1, kn, 128); stB((BUF) ^ 1, kn, 192);                          \
    VMCNT(8);                                                                  \
    BAR();                                                                     \
    av[0] = ldf(lab, rowA0);      av[1] = ldf(lab, rowA0 + 16);                \
    bv[0] = ldf(lbb, rowB0);      bv[1] = ldf(lbb, rowB0 + 16);                \
    bv[2] = ldf(lbb, rowB0 + 32); bv[3] = ldf(lbb, rowB0 + 48);                \
    PRIO1();                                                                   \
    acc[0][0] = MFMA_MX(av[0], bv[0], acc[0][0]);                              \
    acc[0][1] = MFMA_MX(av[0], bv[1], acc[0][1]);                              \
    acc[1][0] = MFMA_MX(av[1], bv[0], acc[1][0]);                              \
    acc[1][1] = MFMA_MX(av[1], bv[1], acc[1][1]);                              \
    PRIO0();                                                                   \
    av[2] = ldf(lab, rowA0 + 32); av[3] = ldf(lab, rowA0 + 48);                \
    PRIO1();                                                                   \
    acc[0][2] = MFMA_MX(av[0], bv[2], acc[0][2]);                              \
    acc[0][3] = MFMA_MX(av[0], bv[3], acc[0][3]);                              \
    acc[1][2] = MFMA_MX(av[1], bv[2], acc[1][2]);                              \
    acc[1][3] = MFMA_MX(av[1], bv[3], acc[1][3]);                              \
    PRIO0();                                                                   \
    av[0] = ldf(lab, rowA0 + 64); av[1] = ldf(lab, rowA0 + 80);                \
    PRIO1();                                                                   \
    acc[2][0] = MFMA_MX(av[2], bv[0], acc[2][0]);                              \
    acc[2][1] = MFMA_MX(av[2], bv[1], acc[2][1]);                              \
    acc[3][0] = MFMA_MX(av[3], bv[0], acc[3][0]);                              \
    acc[3][1] = MFMA_MX(av[3], bv[1], acc[3][1]);                              \
    acc[2][2] = MFMA_MX(av[2], bv[2], acc[2][2]);                              \
    acc[2][3] = MFMA_MX(av[2], bv[3], acc[2][3]);                              \
    acc[3][2] = MFMA_MX(av[3], bv[2], acc[3][2]);                              \
    acc[3][3] = MFMA_MX(av[3], bv[3], acc[3][3]);                              \
    PRIO0();                                                                   \
    av[2] = ldf(lab, rowA0 + 96); av[3] = ldf(lab, rowA0 + 112);               \
    PRIO1();                                                                   \
    acc[4][0] = MFMA_MX(av[0], bv[0], acc[4][0]);                              \
    acc[4][1] = MFMA_MX(av[0], bv[1], acc[4][1]);                              \
    acc[5][0] = MFMA_MX(av[1], bv[0], acc[5][0]);                              \
    acc[5][1] = MFMA_MX(av[1], bv[1], acc[5][1]);                              \
    acc[4][2] = MFMA_MX(av[0], bv[2], acc[4][2]);                              \
    acc[4][3] = MFMA_MX(av[0], bv[3], acc[4][3]);                              \
    acc[5][2] = MFMA_MX(av[1], bv[2], acc[5][2]);                              \
    acc[5][3] = MFMA_MX(av[1], bv[3], acc[5][3]);                              \
    acc[6][0] = MFMA_MX(av[2], bv[0], acc[6][0]);                              \
    acc[6][1] = MFMA_MX(av[2], bv[1], acc[6][1]);                              \
    acc[7][0] = MFMA_MX(av[3], bv[0], acc[7][0]);                              \
    acc[7][1] = MFMA_MX(av[3], bv[1], acc[7][1]);                              \
    acc[6][2] = MFMA_MX(av[2], bv[2], acc[6][2]);                              \
    acc[6][3] = MFMA_MX(av[2], bv[3], acc[6][3]);                              \
    acc[7][2] = MFMA_MX(av[3], bv[2], acc[7][2]);                              \
    acc[7][3] = MFMA_MX(av[3], bv[3], acc[7][3]);                              \
    PRIO0();                                                                   \
  }

__global__ __launch_bounds__(512, 2) void gemm_fp8_kernel(
    const uint8_t* __restrict__ Aq,   // [M][K] fp8
    const uint8_t* __restrict__ Bq,   // [N][K] fp8
    const float* __restrict__ bias,   // [N]
    const unsigned int* __restrict__ ws_u,
    float* __restrict__ out)          // [M][N] f32
{
    __shared__ uint8_t lds[131072];

    const int tid = threadIdx.x;
    const int w = tid >> 6, l = tid & 63;

    // XCD swizzle (512 blocks, %8==0): 32 M-tiles x 16 N-tiles
    const int cpx = (int)gridDim.x >> 3;
    const int bid = (int)blockIdx.x;
    const int swz = (bid & 7) * cpx + (bid >> 3);
    const int bm = swz >> 4, bn = swz & 15;

    const uint8_t* gA = Aq + (size_t)bm * 256 * K_DIM;
    const uint8_t* gB = Bq + (size_t)bn * 256 * K_DIM;

    // staging: thread t -> rows idx+{0,64,128,192}; dest chunk p; src p^(row&7)
    const int idx = tid >> 3, p = tid & 7;
    const int srcX = ((p ^ (idx & 7)) << 4);
    const uint8_t* aRow = gA + (size_t)idx * K_DIM + srcX;
    const uint8_t* bRow = gB + (size_t)idx * K_DIM + srcX;
    const int dA = tid * 16;

    // fragment constants
    const int wr = w >> 2, wc = w & 3;       // 2M x 4N wave grid, 128x64 per wave
    const int lr = l & 15, g = l >> 4;
    const int oLo = (((2 * g) ^ (lr & 7)) << 4);
    const int oHi = (((2 * g + 1) ^ (lr & 7)) << 4);
    const int rowA0 = wr * 128 + lr;
    const int rowB0 = wc * 64 + lr;

    auto stA = [&](int bb, int kn, int rbase) {
        gld16(aRow + (size_t)rbase * K_DIM + kn,
              &lds[bb * 32768 + rbase * 128 + dA]);
    };
    auto stB = [&](int bb, int kn, int rbase) {
        gld16(bRow + (size_t)rbase * K_DIM + kn,
              &lds[65536 + bb * 32768 + rbase * 128 + dA]);
    };
    auto ldf = [&](const uint8_t* base, int row) -> i32x8 {
        const uint8_t* q = base + (row << 7);
        i32x4 lo = *(const i32x4*)(q + oLo);
        i32x4 hi = *(const i32x4*)(q + oHi);
        return __builtin_shufflevector(lo, hi, 0, 1, 2, 3, 4, 5, 6, 7);
    };

    f32x4 acc[8][4] = {};
    i32x8 av[4], bv[4];

    // prologue: stage tile 0 -> buf 0 (8 ops outstanding)
    stA(0, 0, 0);   stA(0, 0, 64);
    stA(0, 0, 128); stA(0, 0, 192);
    stB(0, 0, 0);   stB(0, 0, 64);
    stB(0, 0, 128); stB(0, 0, 192);

    for (int t = 0; t < 30; t += 2) {
        TILE_BODY(t, 0);
        TILE_BODY(t + 1, 1);
    }
    TILE_BODY(30, 0);          // stages tile 31 -> buf 1

    // ---- peeled last tile (t=31, buf=1): no staging; drain
    {
        const uint8_t* lab = &lds[32768];
        const uint8_t* lbb = &lds[65536 + 32768];
        BAR();
        VMCNT(0);
        BAR();
        av[0] = ldf(lab, rowA0);      av[1] = ldf(lab, rowA0 + 16);
        av[2] = ldf(lab, rowA0 + 32); av[3] = ldf(lab, rowA0 + 48);
        bv[0] = ldf(lbb, rowB0);      bv[1] = ldf(lbb, rowB0 + 16);
        bv[2] = ldf(lbb, rowB0 + 32); bv[3] = ldf(lbb, rowB0 + 48);
#pragma unroll
        for (int m = 0; m < 4; ++m) {
            acc[m][0] = MFMA_MX(av[m], bv[0], acc[m][0]);
            acc[m][1] = MFMA_MX(av[m], bv[1], acc[m][1]);
            acc[m][2] = MFMA_MX(av[m], bv[2], acc[m][2]);
            acc[m][3] = MFMA_MX(av[m], bv[3], acc[m][3]);
        }
        av[0] = ldf(lab, rowA0 + 64); av[1] = ldf(lab, rowA0 + 80);
        av[2] = ldf(lab, rowA0 + 96); av[3] = ldf(lab, rowA0 + 112);
#pragma unroll
        for (int m = 0; m < 4; ++m) {
            acc[4 + m][0] = MFMA_MX(av[m], bv[0], acc[4 + m][0]);
            acc[4 + m][1] = MFMA_MX(av[m], bv[1], acc[4 + m][1]);
            acc[4 + m][2] = MFMA_MX(av[m], bv[2], acc[4 + m][2]);
            acc[4 + m][3] = MFMA_MX(av[m], bv[3], acc[4 + m][3]);
        }
    }

    // ---- epilogue: scale by (amax_x/448)*(amax_w/448), add bias
    const float ax = fmaxf(__uint_as_float(ws_u[0]), 1e-12f);
    const float aw = fmaxf(__uint_as_float(ws_u[1]), 1e-12f);
    const float inv = (ax * (1.0f / 448.0f)) * (aw * (1.0f / 448.0f));

    const int orow0 = bm * 256 + wr * 128 + g * 4;   // D: row=(lane>>4)*4+reg
    const int ocol0 = bn * 256 + wc * 64 + lr;       // D: col=lane&15
#pragma unroll
    for (int mb = 0; mb < 8; ++mb) {
#pragma unroll
        for (int nb = 0; nb < 4; ++nb) {
            const int col = ocol0 + nb * 16;
            const float bvv = bias[col];
#pragma unroll
            for (int j = 0; j < 4; ++j) {
                const int row = orow0 + mb * 16 + j;
                out[(size_t)row * N_DIM + col] = acc[mb][nb][j] * inv + bvv;
            }
        }
    }
}

// ---------------- launch ----------------
extern "C" void kernel_launch(void* const* d_in, const int* in_sizes, int n_in,
                              void* d_out, int out_size, void* d_ws, size_t ws_size,
                              hipStream_t stream) {
    const float* x    = (const float*)d_in[0];   // [8192, 4096]
    const float* wgt  = (const float*)d_in[1];   // [4096, 4096]
    const float* bias = (const float*)d_in[2];   // [4096]
    float* out = (float*)d_out;                  // [8192, 4096] f32

    unsigned int* ws_u = (unsigned int*)d_ws;
    uint8_t* xq = (uint8_t*)d_ws + 256;
    uint8_t* wq = xq + (size_t)M_DIM * K_DIM;

    hipMemsetAsync(d_ws, 0, 8, stream);          // zero both amax slots

    dim3 ga(1024, 2);
    amax2_kernel<<<ga, 256, 0, stream>>>(x, wgt, ws_u);

    dim3 gq(2048, 2);
    quant2_kernel<<<gq, 256, 0, stream>>>(x, wgt, (unsigned int*)xq,
                                          (unsigned int*)wq, ws_u);

    gemm_fp8_kernel<<<(M_DIM / 256) * (N_DIM / 256), 512, 0, stream>>>(
        xq, wq, bias, ws_u, out);
}

// Round 9
// 230.580 us; speedup vs baseline: 1.5778x; 1.5778x over previous
//
#include <hip/hip_runtime.h>
#include <stdint.h>

#define M_DIM 8192
#define N_DIM 4096
#define K_DIM 4096

typedef float f32x4 __attribute__((ext_vector_type(4)));
typedef int   i32x4 __attribute__((ext_vector_type(4)));
typedef int   i32x8 __attribute__((ext_vector_type(8)));

// ---------------- fused amax (x and w) via uint-bits atomicMax ----------------
__global__ __launch_bounds__(256) void amax2_kernel(const float* __restrict__ x,
                                                    const float* __restrict__ wgt,
                                                    unsigned int* __restrict__ ws_u) {
    const int which = blockIdx.y;
    const float4* p = (const float4*)(which ? wgt : x);
    const int n4 = (which ? N_DIM : M_DIM) * (K_DIM / 4);
    int tid = blockIdx.x * blockDim.x + threadIdx.x;
    int stride = gridDim.x * blockDim.x;
    float m = 0.0f;
    for (int i = tid; i < n4; i += stride) {
        float4 v = p[i];
        m = fmaxf(m, fmaxf(fmaxf(fabsf(v.x), fabsf(v.y)),
                           fmaxf(fabsf(v.z), fabsf(v.w))));
    }
#pragma unroll
    for (int off = 32; off > 0; off >>= 1)
        m = fmaxf(m, __shfl_down(m, off, 64));
    __shared__ float sm[4];
    if ((threadIdx.x & 63) == 0) sm[threadIdx.x >> 6] = m;
    __syncthreads();
    if (threadIdx.x == 0) {
        m = fmaxf(fmaxf(sm[0], sm[1]), fmaxf(sm[2], sm[3]));
        atomicMax(ws_u + which, __float_as_uint(m));  // values >= 0: bit order == float order
    }
}

// ---------------- fused quantize f32 -> fp8 e4m3fn (packed 4/uint) -------------
__global__ __launch_bounds__(256) void quant2_kernel(const float* __restrict__ x,
                                                     const float* __restrict__ wgt,
                                                     unsigned int* __restrict__ xq,
                                                     unsigned int* __restrict__ wq,
                                                     const unsigned int* __restrict__ ws_u) {
    const int which = blockIdx.y;
    const float4* p = (const float4*)(which ? wgt : x);
    unsigned int* outp = which ? wq : xq;
    const int n4 = (which ? N_DIM : M_DIM) * (K_DIM / 4);
    float amax = fmaxf(__uint_as_float(ws_u[which]), 1e-12f);
    float scale = 448.0f / amax;
    int tid = blockIdx.x * blockDim.x + threadIdx.x;
    int stride = gridDim.x * blockDim.x;
    for (int i = tid; i < n4; i += stride) {
        float4 v = p[i];
        float a = fminf(fmaxf(v.x * scale, -448.0f), 448.0f);
        float b = fminf(fmaxf(v.y * scale, -448.0f), 448.0f);
        float c = fminf(fmaxf(v.z * scale, -448.0f), 448.0f);
        float d = fminf(fmaxf(v.w * scale, -448.0f), 448.0f);
        int w = __builtin_amdgcn_cvt_pk_fp8_f32(a, b, 0, false);
        w = __builtin_amdgcn_cvt_pk_fp8_f32(c, d, w, true);
        outp[i] = (unsigned int)w;
    }
}

// ---------------- MX-fp8 GEMM: 256x128 tile, 2 blocks/CU, occupancy-overlap ----
__device__ __forceinline__ void gld16(const void* g, void* l) {
    __builtin_amdgcn_global_load_lds(
        (const __attribute__((address_space(1))) void*)g,
        (__attribute__((address_space(3))) void*)l, 16, 0, 0);
}

#define MFMA_MX(a, b, c) __builtin_amdgcn_mfma_scale_f32_16x16x128_f8f6f4( \
    (a), (b), (c), 0, 0, 0, 0x7F7F7F7F, 0, 0x7F7F7F7F)
#define BAR()    __builtin_amdgcn_s_barrier()
#define VMCNT(n) asm volatile("s_waitcnt vmcnt(" #n ")" ::: "memory")
#define PRIO1()  __builtin_amdgcn_s_setprio(1)
#define PRIO0()  __builtin_amdgcn_s_setprio(0)

// Block tile 256x128, 8 waves (4M x 2N), wave tile 64x64 -> acc 64 regs/lane.
// __launch_bounds__(512,4) forces <=128 VGPR/wave -> 16 waves/CU -> 2 blocks
// co-resident (LDS 48KB x 2 = 96KB <= 160KB). SINGLE-buffered LDS: per tile
// {vmcnt(0); bar; reads||MFMA; bar; stage(t+1)} -- the drain bubble is hidden
// by the OTHER block's compute phase (cross-block overlap; R2/m114 mechanism).
// Swizzle unchanged (chunk ^= row&7, pre-swizzled global src, XOR on read).
// Liveness capped: av[4] + bv[2] (reused) = 48 frag regs + 64 acc + addr.
__global__ __launch_bounds__(512, 4) void gemm_fp8_kernel(
    const uint8_t* __restrict__ Aq,   // [M][K] fp8
    const uint8_t* __restrict__ Bq,   // [N][K] fp8
    const float* __restrict__ bias,   // [N]
    const unsigned int* __restrict__ ws_u,
    float* __restrict__ out)          // [M][N] f32
{
    __shared__ uint8_t lds[49152];    // A [0,32K), B [32K,48K)

    const int tid = threadIdx.x;
    const int w = tid >> 6, l = tid & 63;

    // XCD swizzle (1024 blocks, %8==0): 32 M-tiles x 32 N-tiles
    const int cpx = (int)gridDim.x >> 3;
    const int bid = (int)blockIdx.x;
    const int swz = (bid & 7) * cpx + (bid >> 3);
    const int bm = swz >> 5, bn = swz & 31;

    const uint8_t* gA = Aq + (size_t)bm * 256 * K_DIM;
    const uint8_t* gB = Bq + (size_t)bn * 128 * K_DIM;

    // staging: thread t -> row idx(+64r); dest chunk p; src chunk p^(idx&7)
    const int idx = tid >> 3, p = tid & 7;
    const int srcX = ((p ^ (idx & 7)) << 4);
    const uint8_t* aRow = gA + (size_t)idx * K_DIM + srcX;
    const uint8_t* bRow = gB + (size_t)idx * K_DIM + srcX;
    const int dA = tid * 16;

    // fragment constants: 4M x 2N wave grid, 64x64 per wave
    const int wr = w >> 1, wc = w & 1;
    const int lr = l & 15, g = l >> 4;
    const int oLo = (((2 * g) ^ (lr & 7)) << 4);
    const int oHi = (((2 * g + 1) ^ (lr & 7)) << 4);
    const int rowA0 = wr * 64 + lr;
    const int rowB0 = wc * 64 + lr;

    auto stage = [&](int kn) {
        gld16(aRow + kn,                          &lds[dA]);
        gld16(aRow + (size_t)64  * K_DIM + kn,    &lds[8192 + dA]);
        gld16(aRow + (size_t)128 * K_DIM + kn,    &lds[16384 + dA]);
        gld16(aRow + (size_t)192 * K_DIM + kn,    &lds[24576 + dA]);
        gld16(bRow + kn,                          &lds[32768 + dA]);
        gld16(bRow + (size_t)64  * K_DIM + kn,    &lds[40960 + dA]);
    };
    auto ldfA = [&](int row) -> i32x8 {
        const uint8_t* q = &lds[row << 7];
        i32x4 lo = *(const i32x4*)(q + oLo);
        i32x4 hi = *(const i32x4*)(q + oHi);
        return __builtin_shufflevector(lo, hi, 0, 1, 2, 3, 4, 5, 6, 7);
    };
    auto ldfB = [&](int row) -> i32x8 {
        const uint8_t* q = &lds[32768 + (row << 7)];
        i32x4 lo = *(const i32x4*)(q + oLo);
        i32x4 hi = *(const i32x4*)(q + oHi);
        return __builtin_shufflevector(lo, hi, 0, 1, 2, 3, 4, 5, 6, 7);
    };

    f32x4 acc[4][4] = {};
    i32x8 av[4], bv[2];

    stage(0);                          // prologue: tile 0

    for (int t = 0; t < 32; ++t) {
        VMCNT(0);                      // own stage writes landed
        BAR();                         // everyone's landed -> tile t readable

        // half 1: cols 0,1
        bv[0] = ldfB(rowB0);      bv[1] = ldfB(rowB0 + 16);
        av[0] = ldfA(rowA0);      av[1] = ldfA(rowA0 + 16);
        av[2] = ldfA(rowA0 + 32); av[3] = ldfA(rowA0 + 48);
        PRIO1();
        acc[0][0] = MFMA_MX(av[0], bv[0], acc[0][0]);
        acc[0][1] = MFMA_MX(av[0], bv[1], acc[0][1]);
        acc[1][0] = MFMA_MX(av[1], bv[0], acc[1][0]);
        acc[1][1] = MFMA_MX(av[1], bv[1], acc[1][1]);
        acc[2][0] = MFMA_MX(av[2], bv[0], acc[2][0]);
        acc[2][1] = MFMA_MX(av[2], bv[1], acc[2][1]);
        acc[3][0] = MFMA_MX(av[3], bv[0], acc[3][0]);
        acc[3][1] = MFMA_MX(av[3], bv[1], acc[3][1]);
        PRIO0();

        // half 2: cols 2,3 (bv regs reused; av persists)
        bv[0] = ldfB(rowB0 + 32); bv[1] = ldfB(rowB0 + 48);
        PRIO1();
        acc[0][2] = MFMA_MX(av[0], bv[0], acc[0][2]);
        acc[0][3] = MFMA_MX(av[0], bv[1], acc[0][3]);
        acc[1][2] = MFMA_MX(av[1], bv[0], acc[1][2]);
        acc[1][3] = MFMA_MX(av[1], bv[1], acc[1][3]);
        acc[2][2] = MFMA_MX(av[2], bv[0], acc[2][2]);
        acc[2][3] = MFMA_MX(av[2], bv[1], acc[2][3]);
        acc[3][2] = MFMA_MX(av[3], bv[0], acc[3][2]);
        acc[3][3] = MFMA_MX(av[3], bv[1], acc[3][3]);
        PRIO0();

        BAR();                         // all waves' ds_reads of tile t retired
        if (t < 31) stage((t + 1) * 128);  // safe overwrite; drain at next top
    }

    // ---- epilogue: scale by (amax_x/448)*(amax_w/448), add bias
    const float ax = fmaxf(__uint_as_float(ws_u[0]), 1e-12f);
    const float aw = fmaxf(__uint_as_float(ws_u[1]), 1e-12f);
    const float inv = (ax * (1.0f / 448.0f)) * (aw * (1.0f / 448.0f));

    const int orow0 = bm * 256 + wr * 64 + g * 4;    // D: row=(lane>>4)*4+reg
    const int ocol0 = bn * 128 + wc * 64 + lr;       // D: col=lane&15
#pragma unroll
    for (int mb = 0; mb < 4; ++mb) {
#pragma unroll
        for (int nb = 0; nb < 4; ++nb) {
            const int col = ocol0 + nb * 16;
            const float bvv = bias[col];
#pragma unroll
            for (int j = 0; j < 4; ++j) {
                const int row = orow0 + mb * 16 + j;
                out[(size_t)row * N_DIM + col] = acc[mb][nb][j] * inv + bvv;
            }
        }
    }
}

// ---------------- launch ----------------
extern "C" void kernel_launch(void* const* d_in, const int* in_sizes, int n_in,
                              void* d_out, int out_size, void* d_ws, size_t ws_size,
                              hipStream_t stream) {
    const float* x    = (const float*)d_in[0];   // [8192, 4096]
    const float* wgt  = (const float*)d_in[1];   // [4096, 4096]
    const float* bias = (const float*)d_in[2];   // [4096]
    float* out = (float*)d_out;                  // [8192, 4096] f32

    unsigned int* ws_u = (unsigned int*)d_ws;
    uint8_t* xq = (uint8_t*)d_ws + 256;
    uint8_t* wq = xq + (size_t)M_DIM * K_DIM;

    hipMemsetAsync(d_ws, 0, 8, stream);          // zero both amax slots

    dim3 ga(1024, 2);
    amax2_kernel<<<ga, 256, 0, stream>>>(x, wgt, ws_u);

    dim3 gq(2048, 2);
    quant2_kernel<<<gq, 256, 0, stream>>>(x, wgt, (unsigned int*)xq,
                                          (unsigned int*)wq, ws_u);

    gemm_fp8_kernel<<<(M_DIM / 256) * (N_DIM / 128), 512, 0, stream>>>(
        xq, wq, bias, ws_u, out);
}

// Round 10
// 215.756 us; speedup vs baseline: 1.6863x; 1.0687x over previous
//
#include <hip/hip_runtime.h>
#include <stdint.h>

#define M_DIM 8192
#define N_DIM 4096
#define K_DIM 4096

typedef float f32x4  __attribute__((ext_vector_type(4)));
typedef float f32x16 __attribute__((ext_vector_type(16)));
typedef int   i32x4  __attribute__((ext_vector_type(4)));
typedef int   i32x8  __attribute__((ext_vector_type(8)));

// ---------------- fused amax (x and w) via uint-bits atomicMax ----------------
__global__ __launch_bounds__(256) void amax2_kernel(const float* __restrict__ x,
                                                    const float* __restrict__ wgt,
                                                    unsigned int* __restrict__ ws_u) {
    const int which = blockIdx.y;
    const float4* p = (const float4*)(which ? wgt : x);
    const int n4 = (which ? N_DIM : M_DIM) * (K_DIM / 4);
    int tid = blockIdx.x * blockDim.x + threadIdx.x;
    int stride = gridDim.x * blockDim.x;
    float m = 0.0f;
    for (int i = tid; i < n4; i += stride) {
        float4 v = p[i];
        m = fmaxf(m, fmaxf(fmaxf(fabsf(v.x), fabsf(v.y)),
                           fmaxf(fabsf(v.z), fabsf(v.w))));
    }
#pragma unroll
    for (int off = 32; off > 0; off >>= 1)
        m = fmaxf(m, __shfl_down(m, off, 64));
    __shared__ float sm[4];
    if ((threadIdx.x & 63) == 0) sm[threadIdx.x >> 6] = m;
    __syncthreads();
    if (threadIdx.x == 0) {
        m = fmaxf(fmaxf(sm[0], sm[1]), fmaxf(sm[2], sm[3]));
        atomicMax(ws_u + which, __float_as_uint(m));  // values >= 0: bit order == float order
    }
}

// ---------------- fused quantize f32 -> fp8 e4m3fn (packed 4/uint) -------------
__global__ __launch_bounds__(256) void quant2_kernel(const float* __restrict__ x,
                                                     const float* __restrict__ wgt,
                                                     unsigned int* __restrict__ xq,
                                                     unsigned int* __restrict__ wq,
                                                     const unsigned int* __restrict__ ws_u) {
    const int which = blockIdx.y;
    const float4* p = (const float4*)(which ? wgt : x);
    unsigned int* outp = which ? wq : xq;
    const int n4 = (which ? N_DIM : M_DIM) * (K_DIM / 4);
    float amax = fmaxf(__uint_as_float(ws_u[which]), 1e-12f);
    float scale = 448.0f / amax;
    int tid = blockIdx.x * blockDim.x + threadIdx.x;
    int stride = gridDim.x * blockDim.x;
    for (int i = tid; i < n4; i += stride) {
        float4 v = p[i];
        float a = fminf(fmaxf(v.x * scale, -448.0f), 448.0f);
        float b = fminf(fmaxf(v.y * scale, -448.0f), 448.0f);
        float c = fminf(fmaxf(v.z * scale, -448.0f), 448.0f);
        float d = fminf(fmaxf(v.w * scale, -448.0f), 448.0f);
        int w = __builtin_amdgcn_cvt_pk_fp8_f32(a, b, 0, false);
        w = __builtin_amdgcn_cvt_pk_fp8_f32(c, d, w, true);
        outp[i] = (unsigned int)w;
    }
}

// ------- MX-fp8 GEMM: 256x256 tile, 4 waves, 128x128/wave, 32x32x64 MFMA -------
__device__ __forceinline__ void gld16(const void* g, void* l) {
    __builtin_amdgcn_global_load_lds(
        (const __attribute__((address_space(1))) void*)g,
        (__attribute__((address_space(3))) void*)l, 16, 0, 0);
}

#define MFMA32(a, b, c) __builtin_amdgcn_mfma_scale_f32_32x32x64_f8f6f4( \
    (a), (b), (c), 0, 0, 0, 0x7F7F7F7F, 0, 0x7F7F7F7F)
#define BAR()    __builtin_amdgcn_s_barrier()
#define VMCNT(n) asm volatile("s_waitcnt vmcnt(" #n ")" ::: "memory")
#define PRIO1()  __builtin_amdgcn_s_setprio(1)
#define PRIO0()  __builtin_amdgcn_s_setprio(0)
#define FENCE()  asm volatile("" ::: "memory")

// Geometry: block 256x256, 4 waves (2x2), wave tile 128x128 -> A,B each
// re-read only 2x: 128 ds_read_b128/tile (-33% vs R4). MFMA 32x32x64 (69 cyc)
// gives long matrix-pipe clusters for intra-wave DS||MFMA overlap (1 wave/SIMD).
// LDS: A bufs [0,32K),[32K,64K); B [64K,96K),[96K,128K); [256 rows][128 B],
// 16B-chunk XOR swizzle (chunk ^= row&7), linear dest / pre-swizzled src /
// XOR on read (rule #21). ONE barrier + ONE vmcnt(0) per tile: all of tile
// t's 16 stages are issued inside t-1's body (P0/P1, after t-1's BAR), so at
// t's vmcnt(0) nothing but needed data is in flight (slack ~3 phases > HBM
// latency). Race audit: each wave's nbuf ds_reads are consumed by MFMAs
// (register deps force lgkmcnt) before it can reach the BAR; stages into nbuf
// only issue after the BAR. Phases fenced (asm memory) so <=12 ds_reads are
// outstanding -> compiler's counted lgkmcnt stays in its 4-bit range (R5's
// 24-outstanding burst forced serial drains).
__global__ __launch_bounds__(256, 1) void gemm_fp8_kernel(
    const uint8_t* __restrict__ Aq,   // [M][K] fp8
    const uint8_t* __restrict__ Bq,   // [N][K] fp8
    const float* __restrict__ bias,   // [N]
    const unsigned int* __restrict__ ws_u,
    float* __restrict__ out)          // [M][N] f32
{
    __shared__ uint8_t lds[131072];

    const int tid = threadIdx.x;
    const int w = tid >> 6, l = tid & 63;

    // XCD swizzle (512 blocks, %8==0): 32 M-tiles x 16 N-tiles
    const int cpx = (int)gridDim.x >> 3;
    const int bid = (int)blockIdx.x;
    const int swz = (bid & 7) * cpx + (bid >> 3);
    const int bm = swz >> 4, bn = swz & 15;

    const uint8_t* gA = Aq + (size_t)bm * 256 * K_DIM;
    const uint8_t* gB = Bq + (size_t)bn * 256 * K_DIM;

    // staging: thread t -> row half*128 + r*32 + idx; dest chunk p; src p^(idx&7)
    const int idx = tid >> 3, p = tid & 7;
    const int srcX = ((p ^ (idx & 7)) << 4);
    const uint8_t* aRow = gA + (size_t)idx * K_DIM + srcX;
    const uint8_t* bRow = gB + (size_t)idx * K_DIM + srcX;
    const int dA = tid * 16;

    // fragment constants: 2x2 wave grid, 128x128 per wave, 32x32 frags
    const int wr = w >> 1, wc = w & 1;
    const int lr = l & 31;           // A row / B col lane index
    const int hi2 = (l >> 5) << 1;   // k-chunk pair select within k-half
    const int rowA0 = wr * 128 + lr;
    const int rowB0 = wc * 128 + lr;

    auto stageA = [&](int bb, int kn, int half) {
#pragma unroll
        for (int r = 0; r < 4; ++r)
            gld16(aRow + (size_t)(half * 128 + r * 32) * K_DIM + kn,
                  &lds[bb * 32768 + half * 16384 + r * 4096 + dA]);
    };
    auto stageB = [&](int bb, int kn, int half) {
#pragma unroll
        for (int r = 0; r < 4; ++r)
            gld16(bRow + (size_t)(half * 128 + r * 32) * K_DIM + kn,
                  &lds[65536 + bb * 32768 + half * 16384 + r * 4096 + dA]);
    };
    // read 32B frag: global chunks c0,c0+1 of row live at LDS chunks c^rk
    auto ldf = [&](const uint8_t* base, int row, int kh) -> i32x8 {
        const uint8_t* q = base + (row << 7);
        const int rk = row & 7;
        const int c0 = (kh << 2) + hi2;
        i32x4 lo = *(const i32x4*)(q + ((c0 ^ rk) << 4));
        i32x4 hh = *(const i32x4*)(q + (((c0 + 1) ^ rk) << 4));
        return __builtin_shufflevector(lo, hh, 0, 1, 2, 3, 4, 5, 6, 7);
    };

    f32x16 acc[4][4] = {};
    i32x8 av[4], bv[4];

    // prologue: stage tile 0 -> buf 0 (16 ops)
    stageA(0, 0, 0); stageB(0, 0, 0);
    stageA(0, 0, 1); stageB(0, 0, 1);

    for (int t = 0; t < 32; ++t) {
        const int buf = t & 1, nbuf = buf ^ 1;
        const int kn = (t + 1) * 128;
        const uint8_t* lab = &lds[buf * 32768];
        const uint8_t* lbb = &lds[65536 + buf * 32768];

        VMCNT(0);                    // tile t's 16 stages landed (issued >=3 phases ago)
        BAR();                       // all waves: tile t visible, nbuf reads done

        // ---- P0: stage half 0 of t+1; kh0 A0-3 x B0-1
        if (t < 31) { stageA(nbuf, kn, 0); stageB(nbuf, kn, 0); }
        bv[0] = ldf(lbb, rowB0, 0);      bv[1] = ldf(lbb, rowB0 + 32, 0);
        av[0] = ldf(lab, rowA0, 0);      av[1] = ldf(lab, rowA0 + 32, 0);
        av[2] = ldf(lab, rowA0 + 64, 0); av[3] = ldf(lab, rowA0 + 96, 0);
        PRIO1();
        acc[0][0] = MFMA32(av[0], bv[0], acc[0][0]);
        acc[0][1] = MFMA32(av[0], bv[1], acc[0][1]);
        acc[1][0] = MFMA32(av[1], bv[0], acc[1][0]);
        acc[1][1] = MFMA32(av[1], bv[1], acc[1][1]);
        acc[2][0] = MFMA32(av[2], bv[0], acc[2][0]);
        acc[2][1] = MFMA32(av[2], bv[1], acc[2][1]);
        acc[3][0] = MFMA32(av[3], bv[0], acc[3][0]);
        acc[3][1] = MFMA32(av[3], bv[1], acc[3][1]);
        PRIO0();
        FENCE();

        // ---- P1: stage half 1 of t+1; kh0 A0-3 x B2-3
        if (t < 31) { stageA(nbuf, kn, 1); stageB(nbuf, kn, 1); }
        bv[2] = ldf(lbb, rowB0 + 64, 0); bv[3] = ldf(lbb, rowB0 + 96, 0);
        PRIO1();
        acc[0][2] = MFMA32(av[0], bv[2], acc[0][2]);
        acc[0][3] = MFMA32(av[0], bv[3], acc[0][3]);
        acc[1][2] = MFMA32(av[1], bv[2], acc[1][2]);
        acc[1][3] = MFMA32(av[1], bv[3], acc[1][3]);
        acc[2][2] = MFMA32(av[2], bv[2], acc[2][2]);
        acc[2][3] = MFMA32(av[2], bv[3], acc[2][3]);
        acc[3][2] = MFMA32(av[3], bv[2], acc[3][2]);
        acc[3][3] = MFMA32(av[3], bv[3], acc[3][3]);
        PRIO0();
        FENCE();

        // ---- P2: kh1 A0-3 x B0-1
        av[0] = ldf(lab, rowA0, 1);      av[1] = ldf(lab, rowA0 + 32, 1);
        av[2] = ldf(lab, rowA0 + 64, 1); av[3] = ldf(lab, rowA0 + 96, 1);
        bv[0] = ldf(lbb, rowB0, 1);      bv[1] = ldf(lbb, rowB0 + 32, 1);
        PRIO1();
        acc[0][0] = MFMA32(av[0], bv[0], acc[0][0]);
        acc[0][1] = MFMA32(av[0], bv[1], acc[0][1]);
        acc[1][0] = MFMA32(av[1], bv[0], acc[1][0]);
        acc[1][1] = MFMA32(av[1], bv[1], acc[1][1]);
        acc[2][0] = MFMA32(av[2], bv[0], acc[2][0]);
        acc[2][1] = MFMA32(av[2], bv[1], acc[2][1]);
        acc[3][0] = MFMA32(av[3], bv[0], acc[3][0]);
        acc[3][1] = MFMA32(av[3], bv[1], acc[3][1]);
        PRIO0();
        FENCE();

        // ---- P3: kh1 A0-3 x B2-3
        bv[2] = ldf(lbb, rowB0 + 64, 1); bv[3] = ldf(lbb, rowB0 + 96, 1);
        PRIO1();
        acc[0][2] = MFMA32(av[0], bv[2], acc[0][2]);
        acc[0][3] = MFMA32(av[0], bv[3], acc[0][3]);
        acc[1][2] = MFMA32(av[1], bv[2], acc[1][2]);
        acc[1][3] = MFMA32(av[1], bv[3], acc[1][3]);
        acc[2][2] = MFMA32(av[2], bv[2], acc[2][2]);
        acc[2][3] = MFMA32(av[2], bv[3], acc[2][3]);
        acc[3][2] = MFMA32(av[3], bv[2], acc[3][2]);
        acc[3][3] = MFMA32(av[3], bv[3], acc[3][3]);
        PRIO0();
    }

    // ---- epilogue: scale by (amax_x/448)*(amax_w/448), add bias
    const float ax = fmaxf(__uint_as_float(ws_u[0]), 1e-12f);
    const float aw = fmaxf(__uint_as_float(ws_u[1]), 1e-12f);
    const float inv = (ax * (1.0f / 448.0f)) * (aw * (1.0f / 448.0f));

    // 32x32 D: col = lane&31, row = (reg&3) + 8*(reg>>2) + 4*(lane>>5)
    const int orow0 = bm * 256 + wr * 128 + ((l >> 5) << 2);
    const int ocol0 = bn * 256 + wc * 128 + lr;
#pragma unroll
    for (int mb = 0; mb < 4; ++mb) {
#pragma unroll
        for (int nb = 0; nb < 4; ++nb) {
            const int col = ocol0 + nb * 32;
            const float bvv = bias[col];
#pragma unroll
            for (int r = 0; r < 16; ++r) {
                const int row = orow0 + mb * 32 + (r & 3) + ((r >> 2) << 3);
                out[(size_t)row * N_DIM + col] = acc[mb][nb][r] * inv + bvv;
            }
        }
    }
}

// ---------------- launch ----------------
extern "C" void kernel_launch(void* const* d_in, const int* in_sizes, int n_in,
                              void* d_out, int out_size, void* d_ws, size_t ws_size,
                              hipStream_t stream) {
    const float* x    = (const float*)d_in[0];   // [8192, 4096]
    const float* wgt  = (const float*)d_in[1];   // [4096, 4096]
    const float* bias = (const float*)d_in[2];   // [4096]
    float* out = (float*)d_out;                  // [8192, 4096] f32

    unsigned int* ws_u = (unsigned int*)d_ws;
    uint8_t* xq = (uint8_t*)d_ws + 256;
    uint8_t* wq = xq + (size_t)M_DIM * K_DIM;

    hipMemsetAsync(d_ws, 0, 8, stream);          // zero both amax slots

    dim3 ga(1024, 2);
    amax2_kernel<<<ga, 256, 0, stream>>>(x, wgt, ws_u);

    dim3 gq(2048, 2);
    quant2_kernel<<<gq, 256, 0, stream>>>(x, wgt, (unsigned int*)xq,
                                          (unsigned int*)wq, ws_u);

    gemm_fp8_kernel<<<(M_DIM / 256) * (N_DIM / 256), 256, 0, stream>>>(
        xq, wq, bias, ws_u, out);
}